// Round 1
// baseline (486.718 us; speedup 1.0000x reference)
//
#include <hip/hip_runtime.h>
#include <math.h>

// Problem: N nodes (50000), E edges (600000), D=128.
// Q = x@Wq.T; K = x@Wk.T; V = x@Wv.T  (node-level, not edge-level: 12x less work)
// per edge e=(s->d): c = sigmoid(dot(Q[d],K[s])/sqrt(128)); agg[d] += c*V[s]
// out = LN(x + agg@Wo.T + bo) * gamma + beta

#define BM 64

// ---------------- fused QKV projection GEMM (fp32) ----------------
// C[i][j] = sum_d x[i][d] * W[j][d].  Block: 256 thr, 64 rows, all 128 cols.
// Thread (tm=tid/16, tn=tid%16) computes 4 rows x 8 cols (cols tn*4..+3 and 64+tn*4..+3).
__global__ __launch_bounds__(256) void qkv_gemm(
    const float* __restrict__ x,
    const float* __restrict__ Wq, const float* __restrict__ Wk,
    const float* __restrict__ Wv,
    float* __restrict__ Q, float* __restrict__ Kb, float* __restrict__ V,
    int N)
{
    __shared__ float xs[BM][132];   // +4 pad: row stride 132 floats (16B aligned)
    __shared__ float bs[16][128];   // bs[kk][j] = W[j][k0+kk]

    const int tid = threadIdx.x;
    const int row0 = blockIdx.x * BM;

    // stage x tile (64x128) once; reused for all 3 weight matrices
    #pragma unroll
    for (int i = 0; i < 8; ++i) {
        int idx = tid + 256 * i;        // float4 index within tile
        int r = idx >> 5;
        int c4 = idx & 31;
        int gr = row0 + r;
        float4 val = make_float4(0.f, 0.f, 0.f, 0.f);
        if (gr < N) val = ((const float4*)(x + (size_t)gr * 128))[c4];
        *((float4*)&xs[r][c4 * 4]) = val;
    }

    const int tn = tid & 15;
    const int tm = tid >> 4;
    const float* Ws[3] = {Wq, Wk, Wv};
    float* Cs[3] = {Q, Kb, V};

    for (int m = 0; m < 3; ++m) {
        const float* __restrict__ W = Ws[m];
        float acc[4][8];
        #pragma unroll
        for (int i = 0; i < 4; ++i)
            #pragma unroll
            for (int j = 0; j < 8; ++j) acc[i][j] = 0.f;

        for (int k0 = 0; k0 < 128; k0 += 16) {
            __syncthreads();   // protect bs from previous iter's readers (also covers xs stage)
            // stage W[j][k0..k0+15] -> bs[kk][j]; thread t: j=t>>1, 8 floats at k0+(t&1)*8
            {
                int j = tid >> 1;
                int half = tid & 1;
                const float* wp = W + j * 128 + k0 + half * 8;
                float4 a = ((const float4*)wp)[0];
                float4 b = ((const float4*)wp)[1];
                int kk = half * 8;
                bs[kk + 0][j] = a.x; bs[kk + 1][j] = a.y;
                bs[kk + 2][j] = a.z; bs[kk + 3][j] = a.w;
                bs[kk + 4][j] = b.x; bs[kk + 5][j] = b.y;
                bs[kk + 6][j] = b.z; bs[kk + 7][j] = b.w;
            }
            __syncthreads();
            #pragma unroll
            for (int kk = 0; kk < 16; ++kk) {
                float4 b0 = *((float4*)&bs[kk][tn * 4]);
                float4 b1 = *((float4*)&bs[kk][64 + tn * 4]);
                #pragma unroll
                for (int i = 0; i < 4; ++i) {
                    float a = xs[tm * 4 + i][k0 + kk];
                    acc[i][0] += a * b0.x; acc[i][1] += a * b0.y;
                    acc[i][2] += a * b0.z; acc[i][3] += a * b0.w;
                    acc[i][4] += a * b1.x; acc[i][5] += a * b1.y;
                    acc[i][6] += a * b1.z; acc[i][7] += a * b1.w;
                }
            }
        }
        float* __restrict__ C = Cs[m];
        #pragma unroll
        for (int i = 0; i < 4; ++i) {
            int gr = row0 + tm * 4 + i;
            if (gr < N) {
                *((float4*)(C + (size_t)gr * 128 + tn * 4)) =
                    make_float4(acc[i][0], acc[i][1], acc[i][2], acc[i][3]);
                *((float4*)(C + (size_t)gr * 128 + 64 + tn * 4)) =
                    make_float4(acc[i][4], acc[i][5], acc[i][6], acc[i][7]);
            }
        }
    }
}

// ---------------- per-edge attention + scatter-add ----------------
// one 64-lane wave per edge; lane covers elements {lane, lane+64}
__global__ __launch_bounds__(256) void edge_kernel(
    const int* __restrict__ ei,
    const float* __restrict__ Q, const float* __restrict__ K,
    const float* __restrict__ V,
    float* __restrict__ agg, int E)
{
    int wave = blockIdx.x * 4 + (threadIdx.x >> 6);
    int lane = threadIdx.x & 63;
    if (wave >= E) return;
    int s = ei[wave];         // src
    int d = ei[E + wave];     // dst
    const float* __restrict__ q = Q + (size_t)d * 128;
    const float* __restrict__ k = K + (size_t)s * 128;
    const float* __restrict__ v = V + (size_t)s * 128;
    float q0 = q[lane], q1 = q[lane + 64];
    float k0 = k[lane], k1 = k[lane + 64];
    float v0 = v[lane], v1 = v[lane + 64];
    float p = q0 * k0 + q1 * k1;
    #pragma unroll
    for (int off = 32; off > 0; off >>= 1) p += __shfl_xor(p, off);
    // sigmoid(p / sqrt(128))
    float c = 1.f / (1.f + __expf(-p * 0.0883883476483184f));
    atomicAdd(&agg[(size_t)d * 128 + lane], c * v0);
    atomicAdd(&agg[(size_t)d * 128 + lane + 64], c * v1);
}

// ---------------- output GEMM + bias + residual + LayerNorm ----------------
__global__ __launch_bounds__(256) void out_ln_kernel(
    const float* __restrict__ agg, const float* __restrict__ Wo,
    const float* __restrict__ bo, const float* __restrict__ x,
    const float* __restrict__ gamma, const float* __restrict__ beta,
    float* __restrict__ out, int N)
{
    __shared__ float xs[BM][132];
    __shared__ float bs[16][128];

    const int tid = threadIdx.x;
    const int row0 = blockIdx.x * BM;

    #pragma unroll
    for (int i = 0; i < 8; ++i) {
        int idx = tid + 256 * i;
        int r = idx >> 5;
        int c4 = idx & 31;
        int gr = row0 + r;
        float4 val = make_float4(0.f, 0.f, 0.f, 0.f);
        if (gr < N) val = ((const float4*)(agg + (size_t)gr * 128))[c4];
        *((float4*)&xs[r][c4 * 4]) = val;
    }

    const int tn = tid & 15;
    const int tm = tid >> 4;
    float acc[4][8];
    #pragma unroll
    for (int i = 0; i < 4; ++i)
        #pragma unroll
        for (int j = 0; j < 8; ++j) acc[i][j] = 0.f;

    for (int k0 = 0; k0 < 128; k0 += 16) {
        __syncthreads();
        {
            int j = tid >> 1;
            int half = tid & 1;
            const float* wp = Wo + j * 128 + k0 + half * 8;
            float4 a = ((const float4*)wp)[0];
            float4 b = ((const float4*)wp)[1];
            int kk = half * 8;
            bs[kk + 0][j] = a.x; bs[kk + 1][j] = a.y;
            bs[kk + 2][j] = a.z; bs[kk + 3][j] = a.w;
            bs[kk + 4][j] = b.x; bs[kk + 5][j] = b.y;
            bs[kk + 6][j] = b.z; bs[kk + 7][j] = b.w;
        }
        __syncthreads();
        #pragma unroll
        for (int kk = 0; kk < 16; ++kk) {
            float4 b0 = *((float4*)&bs[kk][tn * 4]);
            float4 b1 = *((float4*)&bs[kk][64 + tn * 4]);
            #pragma unroll
            for (int i = 0; i < 4; ++i) {
                float a = xs[tm * 4 + i][k0 + kk];
                acc[i][0] += a * b0.x; acc[i][1] += a * b0.y;
                acc[i][2] += a * b0.z; acc[i][3] += a * b0.w;
                acc[i][4] += a * b1.x; acc[i][5] += a * b1.y;
                acc[i][6] += a * b1.z; acc[i][7] += a * b1.w;
            }
        }
    }

    // h = x + gemm + bo  -> overwrite xs with h
    __syncthreads();
    {
        float4 b0 = *((const float4*)(bo + tn * 4));
        float4 b1 = *((const float4*)(bo + 64 + tn * 4));
        #pragma unroll
        for (int i = 0; i < 4; ++i) {
            int r = tm * 4 + i;
            int gr = row0 + r;
            if (gr < N) {
                float4 x0 = *((const float4*)(x + (size_t)gr * 128 + tn * 4));
                float4 x1 = *((const float4*)(x + (size_t)gr * 128 + 64 + tn * 4));
                float4 h0 = make_float4(acc[i][0] + b0.x + x0.x, acc[i][1] + b0.y + x0.y,
                                        acc[i][2] + b0.z + x0.z, acc[i][3] + b0.w + x0.w);
                float4 h1 = make_float4(acc[i][4] + b1.x + x1.x, acc[i][5] + b1.y + x1.y,
                                        acc[i][6] + b1.z + x1.z, acc[i][7] + b1.w + x1.w);
                *((float4*)&xs[r][tn * 4]) = h0;
                *((float4*)&xs[r][64 + tn * 4]) = h1;
            }
        }
    }
    __syncthreads();

    // LayerNorm: 4 threads per row, each covers 32 cols
    {
        int r = tid >> 2;
        int qd = tid & 3;
        int gr = row0 + r;
        float sum = 0.f, sq = 0.f;
        #pragma unroll
        for (int c = 0; c < 32; c += 4) {
            float4 h = *((float4*)&xs[r][qd * 32 + c]);
            sum += h.x + h.y + h.z + h.w;
            sq += h.x * h.x + h.y * h.y + h.z * h.z + h.w * h.w;
        }
        sum += __shfl_xor(sum, 1); sum += __shfl_xor(sum, 2);
        sq  += __shfl_xor(sq, 1);  sq  += __shfl_xor(sq, 2);
        float mu = sum * (1.f / 128.f);
        float var = sq * (1.f / 128.f) - mu * mu;
        float rs = rsqrtf(var + 1e-5f);
        if (gr < N) {
            #pragma unroll
            for (int c = 0; c < 32; c += 4) {
                float4 h = *((float4*)&xs[r][qd * 32 + c]);
                float4 g = *((const float4*)(gamma + qd * 32 + c));
                float4 b = *((const float4*)(beta + qd * 32 + c));
                float4 o = make_float4((h.x - mu) * rs * g.x + b.x,
                                       (h.y - mu) * rs * g.y + b.y,
                                       (h.z - mu) * rs * g.z + b.z,
                                       (h.w - mu) * rs * g.w + b.w);
                *((float4*)(out + (size_t)gr * 128 + qd * 32 + c)) = o;
            }
        }
    }
}

extern "C" void kernel_launch(void* const* d_in, const int* in_sizes, int n_in,
                              void* d_out, int out_size, void* d_ws, size_t ws_size,
                              hipStream_t stream) {
    const float* x     = (const float*)d_in[0];
    const int*   ei    = (const int*)d_in[1];
    const float* Wq    = (const float*)d_in[2];
    const float* Wk    = (const float*)d_in[3];
    const float* Wv    = (const float*)d_in[4];
    const float* Wo    = (const float*)d_in[5];
    const float* bo    = (const float*)d_in[6];
    const float* gamma = (const float*)d_in[7];
    const float* beta  = (const float*)d_in[8];
    const int N = in_sizes[0] / 128;
    const int E = in_sizes[1] / 2;

    // workspace: Q, K, V, agg  (4 * N * 128 floats = 102.4 MB at N=50000)
    float* ws  = (float*)d_ws;
    float* Q   = ws;
    float* Kb  = Q  + (size_t)N * 128;
    float* V   = Kb + (size_t)N * 128;
    float* agg = V  + (size_t)N * 128;

    hipMemsetAsync(agg, 0, (size_t)N * 128 * sizeof(float), stream);

    const int gq = (N + BM - 1) / BM;
    qkv_gemm<<<gq, 256, 0, stream>>>(x, Wq, Wk, Wv, Q, Kb, V, N);

    const int ge = (E + 3) / 4;   // 4 waves (edges) per 256-thr block
    edge_kernel<<<ge, 256, 0, stream>>>(ei, Q, Kb, V, agg, E);

    out_ln_kernel<<<gq, 256, 0, stream>>>(agg, Wo, bo, x, gamma, beta,
                                          (float*)d_out, N);
}

// Round 2
// 484.578 us; speedup vs baseline: 1.0044x; 1.0044x over previous
//
#include <hip/hip_runtime.h>
#include <math.h>

// Problem: N nodes (50000), E edges (600000), D=128.
// Q = x@Wq.T; K = x@Wk.T; V = x@Wv.T  (node-level, not edge-level: 12x less work)
// per edge e=(s->d): c = sigmoid(dot(Q[d],K[s])/sqrt(128)); agg[d] += c*V[s]
// out = LN(x + agg@Wo.T + bo) * gamma + beta

#define BM 64
#define EPW 8   // edges per wave: 8 independent gather->reduce chains in flight
                // (R1 showed edge_kernel latency-bound: 259 cyc/wave measured,
                //  VALUBusy 30%, HBM 38%, occupancy 84% -> ILP, not occupancy)

// ---------------- fused QKV projection GEMM (fp32) ----------------
// C[i][j] = sum_d x[i][d] * W[j][d].  Block: 256 thr, 64 rows, all 128 cols.
// Thread (tm=tid/16, tn=tid%16) computes 4 rows x 8 cols (cols tn*4..+3 and 64+tn*4..+3).
__global__ __launch_bounds__(256) void qkv_gemm(
    const float* __restrict__ x,
    const float* __restrict__ Wq, const float* __restrict__ Wk,
    const float* __restrict__ Wv,
    float* __restrict__ Q, float* __restrict__ Kb, float* __restrict__ V,
    int N)
{
    __shared__ float xs[BM][132];   // +4 pad: row stride 132 floats (16B aligned)
    __shared__ float bs[16][128];   // bs[kk][j] = W[j][k0+kk]

    const int tid = threadIdx.x;
    const int row0 = blockIdx.x * BM;

    // stage x tile (64x128) once; reused for all 3 weight matrices
    #pragma unroll
    for (int i = 0; i < 8; ++i) {
        int idx = tid + 256 * i;        // float4 index within tile
        int r = idx >> 5;
        int c4 = idx & 31;
        int gr = row0 + r;
        float4 val = make_float4(0.f, 0.f, 0.f, 0.f);
        if (gr < N) val = ((const float4*)(x + (size_t)gr * 128))[c4];
        *((float4*)&xs[r][c4 * 4]) = val;
    }

    const int tn = tid & 15;
    const int tm = tid >> 4;
    const float* Ws[3] = {Wq, Wk, Wv};
    float* Cs[3] = {Q, Kb, V};

    for (int m = 0; m < 3; ++m) {
        const float* __restrict__ W = Ws[m];
        float acc[4][8];
        #pragma unroll
        for (int i = 0; i < 4; ++i)
            #pragma unroll
            for (int j = 0; j < 8; ++j) acc[i][j] = 0.f;

        for (int k0 = 0; k0 < 128; k0 += 16) {
            __syncthreads();   // protect bs from previous iter's readers (also covers xs stage)
            // stage W[j][k0..k0+15] -> bs[kk][j]; thread t: j=t>>1, 8 floats at k0+(t&1)*8
            {
                int j = tid >> 1;
                int half = tid & 1;
                const float* wp = W + j * 128 + k0 + half * 8;
                float4 a = ((const float4*)wp)[0];
                float4 b = ((const float4*)wp)[1];
                int kk = half * 8;
                bs[kk + 0][j] = a.x; bs[kk + 1][j] = a.y;
                bs[kk + 2][j] = a.z; bs[kk + 3][j] = a.w;
                bs[kk + 4][j] = b.x; bs[kk + 5][j] = b.y;
                bs[kk + 6][j] = b.z; bs[kk + 7][j] = b.w;
            }
            __syncthreads();
            #pragma unroll
            for (int kk = 0; kk < 16; ++kk) {
                float4 b0 = *((float4*)&bs[kk][tn * 4]);
                float4 b1 = *((float4*)&bs[kk][64 + tn * 4]);
                #pragma unroll
                for (int i = 0; i < 4; ++i) {
                    float a = xs[tm * 4 + i][k0 + kk];
                    acc[i][0] += a * b0.x; acc[i][1] += a * b0.y;
                    acc[i][2] += a * b0.z; acc[i][3] += a * b0.w;
                    acc[i][4] += a * b1.x; acc[i][5] += a * b1.y;
                    acc[i][6] += a * b1.z; acc[i][7] += a * b1.w;
                }
            }
        }
        float* __restrict__ C = Cs[m];
        #pragma unroll
        for (int i = 0; i < 4; ++i) {
            int gr = row0 + tm * 4 + i;
            if (gr < N) {
                *((float4*)(C + (size_t)gr * 128 + tn * 4)) =
                    make_float4(acc[i][0], acc[i][1], acc[i][2], acc[i][3]);
                *((float4*)(C + (size_t)gr * 128 + 64 + tn * 4)) =
                    make_float4(acc[i][4], acc[i][5], acc[i][6], acc[i][7]);
            }
        }
    }
}

// ---------------- per-edge attention + scatter-add ----------------
// one 64-lane wave per EPW edges; lane covers elements {lane, lane+64}.
// All index loads then all gathers are issued before any reduction so the
// EPW dependency chains overlap (R1: single-edge version was latency-bound).
__global__ __launch_bounds__(256) void edge_kernel(
    const int* __restrict__ ei,
    const float* __restrict__ Q, const float* __restrict__ K,
    const float* __restrict__ V,
    float* __restrict__ agg, int E)
{
    int wave = blockIdx.x * 4 + (threadIdx.x >> 6);
    int lane = threadIdx.x & 63;
    int base = wave * EPW;
    if (base >= E) return;

    if (base + EPW <= E) {
        // fast path: fully unrolled batch of EPW edges
        int s[EPW], d[EPW];
        #pragma unroll
        for (int j = 0; j < EPW; ++j) {
            s[j] = ei[base + j];
            d[j] = ei[E + base + j];
        }
        float q0[EPW], q1[EPW], k0[EPW], k1[EPW], v0[EPW], v1[EPW];
        #pragma unroll
        for (int j = 0; j < EPW; ++j) {
            const float* __restrict__ q = Q + (size_t)d[j] * 128;
            const float* __restrict__ k = K + (size_t)s[j] * 128;
            const float* __restrict__ v = V + (size_t)s[j] * 128;
            q0[j] = q[lane]; q1[j] = q[lane + 64];
            k0[j] = k[lane]; k1[j] = k[lane + 64];
            v0[j] = v[lane]; v1[j] = v[lane + 64];
        }
        float p[EPW];
        #pragma unroll
        for (int j = 0; j < EPW; ++j) p[j] = q0[j] * k0[j] + q1[j] * k1[j];
        #pragma unroll
        for (int off = 32; off > 0; off >>= 1) {
            #pragma unroll
            for (int j = 0; j < EPW; ++j) p[j] += __shfl_xor(p[j], off);
        }
        #pragma unroll
        for (int j = 0; j < EPW; ++j) {
            float c = 1.f / (1.f + __expf(-p[j] * 0.0883883476483184f));
            atomicAdd(&agg[(size_t)d[j] * 128 + lane], c * v0[j]);
            atomicAdd(&agg[(size_t)d[j] * 128 + lane + 64], c * v1[j]);
        }
    } else {
        // remainder path
        for (int e = base; e < E; ++e) {
            int s = ei[e];
            int d = ei[E + e];
            const float* __restrict__ q = Q + (size_t)d * 128;
            const float* __restrict__ k = K + (size_t)s * 128;
            const float* __restrict__ v = V + (size_t)s * 128;
            float q0 = q[lane], q1 = q[lane + 64];
            float k0 = k[lane], k1 = k[lane + 64];
            float v0 = v[lane], v1 = v[lane + 64];
            float p = q0 * k0 + q1 * k1;
            #pragma unroll
            for (int off = 32; off > 0; off >>= 1) p += __shfl_xor(p, off);
            float c = 1.f / (1.f + __expf(-p * 0.0883883476483184f));
            atomicAdd(&agg[(size_t)d * 128 + lane], c * v0);
            atomicAdd(&agg[(size_t)d * 128 + lane + 64], c * v1);
        }
    }
}

// ---------------- output GEMM + bias + residual + LayerNorm ----------------
__global__ __launch_bounds__(256) void out_ln_kernel(
    const float* __restrict__ agg, const float* __restrict__ Wo,
    const float* __restrict__ bo, const float* __restrict__ x,
    const float* __restrict__ gamma, const float* __restrict__ beta,
    float* __restrict__ out, int N)
{
    __shared__ float xs[BM][132];
    __shared__ float bs[16][128];

    const int tid = threadIdx.x;
    const int row0 = blockIdx.x * BM;

    #pragma unroll
    for (int i = 0; i < 8; ++i) {
        int idx = tid + 256 * i;
        int r = idx >> 5;
        int c4 = idx & 31;
        int gr = row0 + r;
        float4 val = make_float4(0.f, 0.f, 0.f, 0.f);
        if (gr < N) val = ((const float4*)(agg + (size_t)gr * 128))[c4];
        *((float4*)&xs[r][c4 * 4]) = val;
    }

    const int tn = tid & 15;
    const int tm = tid >> 4;
    float acc[4][8];
    #pragma unroll
    for (int i = 0; i < 4; ++i)
        #pragma unroll
        for (int j = 0; j < 8; ++j) acc[i][j] = 0.f;

    for (int k0 = 0; k0 < 128; k0 += 16) {
        __syncthreads();
        {
            int j = tid >> 1;
            int half = tid & 1;
            const float* wp = Wo + j * 128 + k0 + half * 8;
            float4 a = ((const float4*)wp)[0];
            float4 b = ((const float4*)wp)[1];
            int kk = half * 8;
            bs[kk + 0][j] = a.x; bs[kk + 1][j] = a.y;
            bs[kk + 2][j] = a.z; bs[kk + 3][j] = a.w;
            bs[kk + 4][j] = b.x; bs[kk + 5][j] = b.y;
            bs[kk + 6][j] = b.z; bs[kk + 7][j] = b.w;
        }
        __syncthreads();
        #pragma unroll
        for (int kk = 0; kk < 16; ++kk) {
            float4 b0 = *((float4*)&bs[kk][tn * 4]);
            float4 b1 = *((float4*)&bs[kk][64 + tn * 4]);
            #pragma unroll
            for (int i = 0; i < 4; ++i) {
                float a = xs[tm * 4 + i][k0 + kk];
                acc[i][0] += a * b0.x; acc[i][1] += a * b0.y;
                acc[i][2] += a * b0.z; acc[i][3] += a * b0.w;
                acc[i][4] += a * b1.x; acc[i][5] += a * b1.y;
                acc[i][6] += a * b1.z; acc[i][7] += a * b1.w;
            }
        }
    }

    // h = x + gemm + bo  -> overwrite xs with h
    __syncthreads();
    {
        float4 b0 = *((const float4*)(bo + tn * 4));
        float4 b1 = *((const float4*)(bo + 64 + tn * 4));
        #pragma unroll
        for (int i = 0; i < 4; ++i) {
            int r = tm * 4 + i;
            int gr = row0 + r;
            if (gr < N) {
                float4 x0 = *((const float4*)(x + (size_t)gr * 128 + tn * 4));
                float4 x1 = *((const float4*)(x + (size_t)gr * 128 + 64 + tn * 4));
                float4 h0 = make_float4(acc[i][0] + b0.x + x0.x, acc[i][1] + b0.y + x0.y,
                                        acc[i][2] + b0.z + x0.z, acc[i][3] + b0.w + x0.w);
                float4 h1 = make_float4(acc[i][4] + b1.x + x1.x, acc[i][5] + b1.y + x1.y,
                                        acc[i][6] + b1.z + x1.z, acc[i][7] + b1.w + x1.w);
                *((float4*)&xs[r][tn * 4]) = h0;
                *((float4*)&xs[r][64 + tn * 4]) = h1;
            }
        }
    }
    __syncthreads();

    // LayerNorm: 4 threads per row, each covers 32 cols
    {
        int r = tid >> 2;
        int qd = tid & 3;
        int gr = row0 + r;
        float sum = 0.f, sq = 0.f;
        #pragma unroll
        for (int c = 0; c < 32; c += 4) {
            float4 h = *((float4*)&xs[r][qd * 32 + c]);
            sum += h.x + h.y + h.z + h.w;
            sq += h.x * h.x + h.y * h.y + h.z * h.z + h.w * h.w;
        }
        sum += __shfl_xor(sum, 1); sum += __shfl_xor(sum, 2);
        sq  += __shfl_xor(sq, 1);  sq  += __shfl_xor(sq, 2);
        float mu = sum * (1.f / 128.f);
        float var = sq * (1.f / 128.f) - mu * mu;
        float rs = rsqrtf(var + 1e-5f);
        if (gr < N) {
            #pragma unroll
            for (int c = 0; c < 32; c += 4) {
                float4 h = *((float4*)&xs[r][qd * 32 + c]);
                float4 g = *((const float4*)(gamma + qd * 32 + c));
                float4 b = *((const float4*)(beta + qd * 32 + c));
                float4 o = make_float4((h.x - mu) * rs * g.x + b.x,
                                       (h.y - mu) * rs * g.y + b.y,
                                       (h.z - mu) * rs * g.z + b.z,
                                       (h.w - mu) * rs * g.w + b.w);
                *((float4*)(out + (size_t)gr * 128 + qd * 32 + c)) = o;
            }
        }
    }
}

extern "C" void kernel_launch(void* const* d_in, const int* in_sizes, int n_in,
                              void* d_out, int out_size, void* d_ws, size_t ws_size,
                              hipStream_t stream) {
    const float* x     = (const float*)d_in[0];
    const int*   ei    = (const int*)d_in[1];
    const float* Wq    = (const float*)d_in[2];
    const float* Wk    = (const float*)d_in[3];
    const float* Wv    = (const float*)d_in[4];
    const float* Wo    = (const float*)d_in[5];
    const float* bo    = (const float*)d_in[6];
    const float* gamma = (const float*)d_in[7];
    const float* beta  = (const float*)d_in[8];
    const int N = in_sizes[0] / 128;
    const int E = in_sizes[1] / 2;

    // workspace: Q, K, V, agg  (4 * N * 128 floats = 102.4 MB at N=50000)
    float* ws  = (float*)d_ws;
    float* Q   = ws;
    float* Kb  = Q  + (size_t)N * 128;
    float* V   = Kb + (size_t)N * 128;
    float* agg = V  + (size_t)N * 128;

    hipMemsetAsync(agg, 0, (size_t)N * 128 * sizeof(float), stream);

    const int gq = (N + BM - 1) / BM;
    qkv_gemm<<<gq, 256, 0, stream>>>(x, Wq, Wk, Wv, Q, Kb, V, N);

    const int waves = (E + EPW - 1) / EPW;
    const int ge = (waves + 3) / 4;   // 4 waves per 256-thr block
    edge_kernel<<<ge, 256, 0, stream>>>(ei, Q, Kb, V, agg, E);

    out_ln_kernel<<<gq, 256, 0, stream>>>(agg, Wo, bo, x, gamma, beta,
                                          (float*)d_out, N);
}

// Round 3
// 389.349 us; speedup vs baseline: 1.2501x; 1.2446x over previous
//
#include <hip/hip_runtime.h>
#include <math.h>

// N nodes (50000), E edges (600000), D=128.
// Q = x@Wq.T; K = x@Wk.T; V = x@Wv.T  (node-level)
// per edge e=(s->d): c = sigmoid(dot(Q[d],K[s])/sqrt(128)); agg[d] += c*V[s]
// out = LN(x + agg@Wo.T + bo) * gamma + beta
//
// R2 post-mortem: per-edge f32 atomicAdd hit the TCC atomic ceiling
// (76.8M atomics / 253us = 303 G/s ~= 128 ch x 2.4 GHz). This version
// counting-sorts edges by dst (int atomics only, ~1.2M ops) and aggregates
// per node with plain stores -- zero f32 atomics.

#define BM 64

// ---------------- fused QKV projection GEMM (fp32) ----------------
__global__ __launch_bounds__(256) void qkv_gemm(
    const float* __restrict__ x,
    const float* __restrict__ Wq, const float* __restrict__ Wk,
    const float* __restrict__ Wv,
    float* __restrict__ Q, float* __restrict__ Kb, float* __restrict__ V,
    int N)
{
    __shared__ float xs[BM][132];
    __shared__ float bs[16][128];

    const int tid = threadIdx.x;
    const int row0 = blockIdx.x * BM;

    #pragma unroll
    for (int i = 0; i < 8; ++i) {
        int idx = tid + 256 * i;
        int r = idx >> 5;
        int c4 = idx & 31;
        int gr = row0 + r;
        float4 val = make_float4(0.f, 0.f, 0.f, 0.f);
        if (gr < N) val = ((const float4*)(x + (size_t)gr * 128))[c4];
        *((float4*)&xs[r][c4 * 4]) = val;
    }

    const int tn = tid & 15;
    const int tm = tid >> 4;
    const float* Ws[3] = {Wq, Wk, Wv};
    float* Cs[3] = {Q, Kb, V};

    for (int m = 0; m < 3; ++m) {
        const float* __restrict__ W = Ws[m];
        float acc[4][8];
        #pragma unroll
        for (int i = 0; i < 4; ++i)
            #pragma unroll
            for (int j = 0; j < 8; ++j) acc[i][j] = 0.f;

        for (int k0 = 0; k0 < 128; k0 += 16) {
            __syncthreads();
            {
                int j = tid >> 1;
                int half = tid & 1;
                const float* wp = W + j * 128 + k0 + half * 8;
                float4 a = ((const float4*)wp)[0];
                float4 b = ((const float4*)wp)[1];
                int kk = half * 8;
                bs[kk + 0][j] = a.x; bs[kk + 1][j] = a.y;
                bs[kk + 2][j] = a.z; bs[kk + 3][j] = a.w;
                bs[kk + 4][j] = b.x; bs[kk + 5][j] = b.y;
                bs[kk + 6][j] = b.z; bs[kk + 7][j] = b.w;
            }
            __syncthreads();
            #pragma unroll
            for (int kk = 0; kk < 16; ++kk) {
                float4 b0 = *((float4*)&bs[kk][tn * 4]);
                float4 b1 = *((float4*)&bs[kk][64 + tn * 4]);
                #pragma unroll
                for (int i = 0; i < 4; ++i) {
                    float a = xs[tm * 4 + i][k0 + kk];
                    acc[i][0] += a * b0.x; acc[i][1] += a * b0.y;
                    acc[i][2] += a * b0.z; acc[i][3] += a * b0.w;
                    acc[i][4] += a * b1.x; acc[i][5] += a * b1.y;
                    acc[i][6] += a * b1.z; acc[i][7] += a * b1.w;
                }
            }
        }
        float* __restrict__ C = Cs[m];
        #pragma unroll
        for (int i = 0; i < 4; ++i) {
            int gr = row0 + tm * 4 + i;
            if (gr < N) {
                *((float4*)(C + (size_t)gr * 128 + tn * 4)) =
                    make_float4(acc[i][0], acc[i][1], acc[i][2], acc[i][3]);
                *((float4*)(C + (size_t)gr * 128 + 64 + tn * 4)) =
                    make_float4(acc[i][4], acc[i][5], acc[i][6], acc[i][7]);
            }
        }
    }
}

// ---------------- counting sort of edges by dst ----------------
__global__ __launch_bounds__(256) void hist_kernel(
    const int* __restrict__ ei, int* __restrict__ hist, int E)
{
    int e = blockIdx.x * blockDim.x + threadIdx.x;
    if (e < E) atomicAdd(&hist[ei[E + e]], 1);
}

#define SCAN_TPB 256
#define SCAN_EPT 4   // 1024 elements per scan block

__global__ __launch_bounds__(SCAN_TPB) void scan_partial(
    const int* __restrict__ hist, int* __restrict__ offs,
    int* __restrict__ blockSums, int N)
{
    __shared__ int sdata[SCAN_TPB];
    int b = blockIdx.x;
    int t = threadIdx.x;
    int base = b * SCAN_TPB * SCAN_EPT + t * SCAN_EPT;
    int v[SCAN_EPT];
    int tot = 0;
    #pragma unroll
    for (int j = 0; j < SCAN_EPT; ++j) {
        int idx = base + j;
        v[j] = (idx < N) ? hist[idx] : 0;
        tot += v[j];
    }
    sdata[t] = tot;
    __syncthreads();
    for (int off = 1; off < SCAN_TPB; off <<= 1) {
        int xv = (t >= off) ? sdata[t - off] : 0;
        __syncthreads();
        sdata[t] += xv;
        __syncthreads();
    }
    int run = sdata[t] - tot;  // exclusive prefix of this thread within block
    #pragma unroll
    for (int j = 0; j < SCAN_EPT; ++j) {
        int idx = base + j;
        if (idx < N) offs[idx] = run;
        run += v[j];
    }
    if (t == SCAN_TPB - 1) blockSums[b] = sdata[t];
}

__global__ __launch_bounds__(256) void scan_blocksums(int* __restrict__ blockSums, int nb)
{
    __shared__ int sdata[256];
    int t = threadIdx.x;
    int orig = (t < nb) ? blockSums[t] : 0;
    sdata[t] = orig;
    __syncthreads();
    for (int off = 1; off < 256; off <<= 1) {
        int xv = (t >= off) ? sdata[t - off] : 0;
        __syncthreads();
        sdata[t] += xv;
        __syncthreads();
    }
    if (t < nb) blockSums[t] = sdata[t] - orig;  // exclusive
}

__global__ __launch_bounds__(256) void scan_add(
    int* __restrict__ offs, const int* __restrict__ blockSums, int N)
{
    int idx = blockIdx.x * blockDim.x + threadIdx.x;
    if (idx < N) offs[idx] += blockSums[idx >> 10];  // 1024 elems per scan block
}

// scatter: offs[d] is consumed (becomes END offset after all increments)
__global__ __launch_bounds__(256) void scatter_kernel(
    const int* __restrict__ ei, int* __restrict__ offs,
    int* __restrict__ ssrc, int E)
{
    int e = blockIdx.x * blockDim.x + threadIdx.x;
    if (e < E) {
        int d = ei[E + e];
        int pos = atomicAdd(&offs[d], 1);
        ssrc[pos] = ei[e];
    }
}

// ---------------- per-node attention aggregation (no atomics) ----------------
// one 64-lane wave per dst node; lane covers elements {lane, lane+64}
__global__ __launch_bounds__(256) void node_agg(
    const int* __restrict__ ssrc,
    const int* __restrict__ endoffs,   // offs after scatter = end offsets
    const int* __restrict__ deg,       // hist = degree
    const float* __restrict__ Q, const float* __restrict__ K,
    const float* __restrict__ V,
    float* __restrict__ agg, int N)
{
    int node = blockIdx.x * 4 + (threadIdx.x >> 6);
    int lane = threadIdx.x & 63;
    if (node >= N) return;
    int end = endoffs[node];
    int start = end - deg[node];
    float q0 = Q[(size_t)node * 128 + lane];
    float q1 = Q[(size_t)node * 128 + lane + 64];
    float a0 = 0.f, a1 = 0.f;
    int i = start;
    for (; i + 4 <= end; i += 4) {
        int s[4];
        #pragma unroll
        for (int j = 0; j < 4; ++j) s[j] = ssrc[i + j];
        float k0[4], k1[4], v0[4], v1[4];
        #pragma unroll
        for (int j = 0; j < 4; ++j) {
            const float* __restrict__ kp = K + (size_t)s[j] * 128;
            const float* __restrict__ vp = V + (size_t)s[j] * 128;
            k0[j] = kp[lane]; k1[j] = kp[lane + 64];
            v0[j] = vp[lane]; v1[j] = vp[lane + 64];
        }
        float p[4];
        #pragma unroll
        for (int j = 0; j < 4; ++j) p[j] = q0 * k0[j] + q1 * k1[j];
        #pragma unroll
        for (int off = 32; off > 0; off >>= 1) {
            #pragma unroll
            for (int j = 0; j < 4; ++j) p[j] += __shfl_xor(p[j], off);
        }
        #pragma unroll
        for (int j = 0; j < 4; ++j) {
            float c = 1.f / (1.f + __expf(-p[j] * 0.0883883476483184f));
            a0 += c * v0[j]; a1 += c * v1[j];
        }
    }
    for (; i < end; ++i) {
        int s = ssrc[i];
        const float* __restrict__ kp = K + (size_t)s * 128;
        const float* __restrict__ vp = V + (size_t)s * 128;
        float k0 = kp[lane], k1 = kp[lane + 64];
        float v0 = vp[lane], v1 = vp[lane + 64];
        float p = q0 * k0 + q1 * k1;
        #pragma unroll
        for (int off = 32; off > 0; off >>= 1) p += __shfl_xor(p, off);
        float c = 1.f / (1.f + __expf(-p * 0.0883883476483184f));
        a0 += c * v0; a1 += c * v1;
    }
    agg[(size_t)node * 128 + lane] = a0;
    agg[(size_t)node * 128 + lane + 64] = a1;
}

// ---------------- output GEMM + bias + residual + LayerNorm ----------------
__global__ __launch_bounds__(256) void out_ln_kernel(
    const float* __restrict__ agg, const float* __restrict__ Wo,
    const float* __restrict__ bo, const float* __restrict__ x,
    const float* __restrict__ gamma, const float* __restrict__ beta,
    float* __restrict__ out, int N)
{
    __shared__ float xs[BM][132];
    __shared__ float bs[16][128];

    const int tid = threadIdx.x;
    const int row0 = blockIdx.x * BM;

    #pragma unroll
    for (int i = 0; i < 8; ++i) {
        int idx = tid + 256 * i;
        int r = idx >> 5;
        int c4 = idx & 31;
        int gr = row0 + r;
        float4 val = make_float4(0.f, 0.f, 0.f, 0.f);
        if (gr < N) val = ((const float4*)(agg + (size_t)gr * 128))[c4];
        *((float4*)&xs[r][c4 * 4]) = val;
    }

    const int tn = tid & 15;
    const int tm = tid >> 4;
    float acc[4][8];
    #pragma unroll
    for (int i = 0; i < 4; ++i)
        #pragma unroll
        for (int j = 0; j < 8; ++j) acc[i][j] = 0.f;

    for (int k0 = 0; k0 < 128; k0 += 16) {
        __syncthreads();
        {
            int j = tid >> 1;
            int half = tid & 1;
            const float* wp = Wo + j * 128 + k0 + half * 8;
            float4 a = ((const float4*)wp)[0];
            float4 b = ((const float4*)wp)[1];
            int kk = half * 8;
            bs[kk + 0][j] = a.x; bs[kk + 1][j] = a.y;
            bs[kk + 2][j] = a.z; bs[kk + 3][j] = a.w;
            bs[kk + 4][j] = b.x; bs[kk + 5][j] = b.y;
            bs[kk + 6][j] = b.z; bs[kk + 7][j] = b.w;
        }
        __syncthreads();
        #pragma unroll
        for (int kk = 0; kk < 16; ++kk) {
            float4 b0 = *((float4*)&bs[kk][tn * 4]);
            float4 b1 = *((float4*)&bs[kk][64 + tn * 4]);
            #pragma unroll
            for (int i = 0; i < 4; ++i) {
                float a = xs[tm * 4 + i][k0 + kk];
                acc[i][0] += a * b0.x; acc[i][1] += a * b0.y;
                acc[i][2] += a * b0.z; acc[i][3] += a * b0.w;
                acc[i][4] += a * b1.x; acc[i][5] += a * b1.y;
                acc[i][6] += a * b1.z; acc[i][7] += a * b1.w;
            }
        }
    }

    __syncthreads();
    {
        float4 b0 = *((const float4*)(bo + tn * 4));
        float4 b1 = *((const float4*)(bo + 64 + tn * 4));
        #pragma unroll
        for (int i = 0; i < 4; ++i) {
            int r = tm * 4 + i;
            int gr = row0 + r;
            if (gr < N) {
                float4 x0 = *((const float4*)(x + (size_t)gr * 128 + tn * 4));
                float4 x1 = *((const float4*)(x + (size_t)gr * 128 + 64 + tn * 4));
                float4 h0 = make_float4(acc[i][0] + b0.x + x0.x, acc[i][1] + b0.y + x0.y,
                                        acc[i][2] + b0.z + x0.z, acc[i][3] + b0.w + x0.w);
                float4 h1 = make_float4(acc[i][4] + b1.x + x1.x, acc[i][5] + b1.y + x1.y,
                                        acc[i][6] + b1.z + x1.z, acc[i][7] + b1.w + x1.w);
                *((float4*)&xs[r][tn * 4]) = h0;
                *((float4*)&xs[r][64 + tn * 4]) = h1;
            }
        }
    }
    __syncthreads();

    {
        int r = tid >> 2;
        int qd = tid & 3;
        int gr = row0 + r;
        float sum = 0.f, sq = 0.f;
        #pragma unroll
        for (int c = 0; c < 32; c += 4) {
            float4 h = *((float4*)&xs[r][qd * 32 + c]);
            sum += h.x + h.y + h.z + h.w;
            sq += h.x * h.x + h.y * h.y + h.z * h.z + h.w * h.w;
        }
        sum += __shfl_xor(sum, 1); sum += __shfl_xor(sum, 2);
        sq  += __shfl_xor(sq, 1);  sq  += __shfl_xor(sq, 2);
        float mu = sum * (1.f / 128.f);
        float var = sq * (1.f / 128.f) - mu * mu;
        float rs = rsqrtf(var + 1e-5f);
        if (gr < N) {
            #pragma unroll
            for (int c = 0; c < 32; c += 4) {
                float4 h = *((float4*)&xs[r][qd * 32 + c]);
                float4 g = *((const float4*)(gamma + qd * 32 + c));
                float4 b = *((const float4*)(beta + qd * 32 + c));
                float4 o = make_float4((h.x - mu) * rs * g.x + b.x,
                                       (h.y - mu) * rs * g.y + b.y,
                                       (h.z - mu) * rs * g.z + b.z,
                                       (h.w - mu) * rs * g.w + b.w);
                *((float4*)(out + (size_t)gr * 128 + qd * 32 + c)) = o;
            }
        }
    }
}

extern "C" void kernel_launch(void* const* d_in, const int* in_sizes, int n_in,
                              void* d_out, int out_size, void* d_ws, size_t ws_size,
                              hipStream_t stream) {
    const float* x     = (const float*)d_in[0];
    const int*   ei    = (const int*)d_in[1];
    const float* Wq    = (const float*)d_in[2];
    const float* Wk    = (const float*)d_in[3];
    const float* Wv    = (const float*)d_in[4];
    const float* Wo    = (const float*)d_in[5];
    const float* bo    = (const float*)d_in[6];
    const float* gamma = (const float*)d_in[7];
    const float* beta  = (const float*)d_in[8];
    const int N = in_sizes[0] / 128;
    const int E = in_sizes[1] / 2;
    const size_t ND = (size_t)N * 128;

    // workspace: Q,K,V,agg (102.4 MB) + hist/offs/blockSums/ssrc (~2.9 MB)
    float* ws  = (float*)d_ws;
    float* Q   = ws;
    float* Kb  = Q  + ND;
    float* V   = Kb + ND;
    float* agg = V  + ND;
    int* hist      = (int*)(agg + ND);
    int* offs      = hist + N;
    int* blockSums = offs + N;        // 256 ints
    int* ssrc      = blockSums + 256; // E ints

    hipMemsetAsync(hist, 0, (size_t)N * sizeof(int), stream);

    const int gq = (N + BM - 1) / BM;
    qkv_gemm<<<gq, 256, 0, stream>>>(x, Wq, Wk, Wv, Q, Kb, V, N);

    // counting sort by dst
    hist_kernel<<<(E + 255) / 256, 256, 0, stream>>>(ei, hist, E);
    const int nScanBlocks = (N + SCAN_TPB * SCAN_EPT - 1) / (SCAN_TPB * SCAN_EPT);
    scan_partial<<<nScanBlocks, SCAN_TPB, 0, stream>>>(hist, offs, blockSums, N);
    scan_blocksums<<<1, 256, 0, stream>>>(blockSums, nScanBlocks);
    scan_add<<<(N + 255) / 256, 256, 0, stream>>>(offs, blockSums, N);
    scatter_kernel<<<(E + 255) / 256, 256, 0, stream>>>(ei, offs, ssrc, E);

    // per-node aggregation, plain stores (offs now holds END offsets)
    node_agg<<<(N + 3) / 4, 256, 0, stream>>>(ssrc, offs, hist, Q, Kb, V, agg, N);

    out_ln_kernel<<<gq, 256, 0, stream>>>(agg, Wo, bo, x, gamma, beta,
                                          (float*)d_out, N);
}

// Round 4
// 319.304 us; speedup vs baseline: 1.5243x; 1.2194x over previous
//
#include <hip/hip_runtime.h>
#include <math.h>

// N nodes (50000), E edges (600000), D=128.
// Q = x@Wq.T; K = x@Wk.T; V = x@Wv.T  (node-level)
// per edge e=(s->d): c = sigmoid(dot(Q[d],K[s])/sqrt(128)); agg[d] += c*V[s]
// out = LN(x + agg@Wo.T + bo) * gamma + beta
//
// R2: per-edge f32 atomics hit TCC atomic ceiling -> counting-sort + per-node agg.
// R3: fp32 VALU GEMMs (44 TF, VALUBusy 31%) -> split-bf16 MFMA GEMMs
//     (C = xh*wh + xl*wh + xh*wl, fp32 acc; rel err ~2^-17, output fp32).

#define BM 64

typedef __attribute__((ext_vector_type(8))) short bfrag;   // 8 bf16 = 4 VGPRs
typedef __attribute__((ext_vector_type(4))) float f32x4;

__device__ __forceinline__ short f2bf(float f) {
    union { float f; unsigned u; } v; v.f = f;
    unsigned r = v.u + 0x7FFFu + ((v.u >> 16) & 1u);   // round-to-nearest-even
    return (short)(r >> 16);
}
__device__ __forceinline__ float bf2f(short h) {
    union { unsigned u; float f; } v;
    v.u = ((unsigned)(unsigned short)h) << 16;
    return v.f;
}

// ---------------- weight prep: fp32 -> bf16 hi/lo, 4 matrices ----------------
// layout: whi[mat*16384 + n*128 + k], mat = {Wq,Wk,Wv,Wo}
__global__ __launch_bounds__(256) void prep_weights(
    const float* __restrict__ Wq, const float* __restrict__ Wk,
    const float* __restrict__ Wv, const float* __restrict__ Wo,
    short* __restrict__ whi, short* __restrict__ wlo)
{
    int g = blockIdx.x * 256 + threadIdx.x;   // grid = 256 blocks -> 65536
    const float* Ws[4] = {Wq, Wk, Wv, Wo};
    float f = Ws[g >> 14][g & 16383];
    short h = f2bf(f);
    short l = f2bf(f - bf2f(h));
    whi[g] = h; wlo[g] = l;
}

// ---------------- fused QKV projection via split-bf16 MFMA ----------------
// block = 256 thr = 4 waves; 64 rows x 128 cols. Wave w covers cols [32w,32w+32).
// A frag: A[m=lane&15][k=quad*8+j]; B frag: B[k=quad*8+j][n=lane&15] = W[n][k];
// C/D: col=lane&15, row=quad*4+reg  (guide-verified layouts, m89/m120).
__global__ __launch_bounds__(256) void qkv_mfma(
    const float* __restrict__ x,
    const short* __restrict__ whi, const short* __restrict__ wlo,
    float* __restrict__ Q, float* __restrict__ Kb, float* __restrict__ V,
    int N)
{
    __shared__ short xs_hi[64][136];   // +8 pad: row 272 B -> 2-way LDS (free)
    __shared__ short xs_lo[64][136];

    const int tid = threadIdx.x;
    const int row0 = blockIdx.x * BM;

    // stage x tile, converting fp32 -> bf16 hi/lo
    #pragma unroll
    for (int i = 0; i < 8; ++i) {
        int idx = tid + 256 * i;
        int r = idx >> 5;
        int c4 = idx & 31;
        int gr = row0 + r;
        float4 val = make_float4(0.f, 0.f, 0.f, 0.f);
        if (gr < N) val = ((const float4*)(x + (size_t)gr * 128))[c4];
        short4 h, l;
        h.x = f2bf(val.x); l.x = f2bf(val.x - bf2f(h.x));
        h.y = f2bf(val.y); l.y = f2bf(val.y - bf2f(h.y));
        h.z = f2bf(val.z); l.z = f2bf(val.z - bf2f(h.z));
        h.w = f2bf(val.w); l.w = f2bf(val.w - bf2f(h.w));
        *((short4*)&xs_hi[r][c4 * 4]) = h;
        *((short4*)&xs_lo[r][c4 * 4]) = l;
    }
    __syncthreads();

    const int wid  = tid >> 6;
    const int lane = tid & 63;
    const int n16  = lane & 15;
    const int quad = lane >> 4;
    float* Cs[3] = {Q, Kb, V};

    #pragma unroll 1
    for (int mat = 0; mat < 3; ++mat) {
        const short* __restrict__ WH = whi + mat * 16384;
        const short* __restrict__ WL = wlo + mat * 16384;
        const f32x4 zero = {0.f, 0.f, 0.f, 0.f};
        f32x4 acc[4][2];
        #pragma unroll
        for (int t = 0; t < 4; ++t) { acc[t][0] = zero; acc[t][1] = zero; }

        #pragma unroll
        for (int kc = 0; kc < 4; ++kc) {
            int k0 = kc * 32 + quad * 8;
            bfrag ah[4], al[4], bh[2], bl[2];
            #pragma unroll
            for (int t = 0; t < 4; ++t) {
                ah[t] = *((const bfrag*)&xs_hi[t * 16 + n16][k0]);
                al[t] = *((const bfrag*)&xs_lo[t * 16 + n16][k0]);
            }
            #pragma unroll
            for (int c = 0; c < 2; ++c) {
                int wr = (wid * 2 + c) * 16 + n16;
                bh[c] = *((const bfrag*)(WH + wr * 128 + k0));
                bl[c] = *((const bfrag*)(WL + wr * 128 + k0));
            }
            #pragma unroll
            for (int t = 0; t < 4; ++t)
                #pragma unroll
                for (int c = 0; c < 2; ++c) {
                    acc[t][c] = __builtin_amdgcn_mfma_f32_16x16x32_bf16(ah[t], bh[c], acc[t][c], 0, 0, 0);
                    acc[t][c] = __builtin_amdgcn_mfma_f32_16x16x32_bf16(al[t], bh[c], acc[t][c], 0, 0, 0);
                    acc[t][c] = __builtin_amdgcn_mfma_f32_16x16x32_bf16(ah[t], bl[c], acc[t][c], 0, 0, 0);
                }
        }
        float* __restrict__ C = Cs[mat];
        #pragma unroll
        for (int t = 0; t < 4; ++t)
            #pragma unroll
            for (int r = 0; r < 4; ++r) {
                int grow = row0 + t * 16 + quad * 4 + r;
                if (grow < N) {
                    C[(size_t)grow * 128 + (wid * 2 + 0) * 16 + n16] = acc[t][0][r];
                    C[(size_t)grow * 128 + (wid * 2 + 1) * 16 + n16] = acc[t][1][r];
                }
            }
    }
}

// ---------------- counting sort of edges by dst ----------------
__global__ __launch_bounds__(256) void hist_kernel(
    const int* __restrict__ ei, int* __restrict__ hist, int E)
{
    int e = blockIdx.x * blockDim.x + threadIdx.x;
    if (e < E) atomicAdd(&hist[ei[E + e]], 1);
}

#define SCAN_TPB 256
#define SCAN_EPT 4   // 1024 elements per scan block

__global__ __launch_bounds__(SCAN_TPB) void scan_partial(
    const int* __restrict__ hist, int* __restrict__ offs,
    int* __restrict__ blockSums, int N)
{
    __shared__ int sdata[SCAN_TPB];
    int b = blockIdx.x;
    int t = threadIdx.x;
    int base = b * SCAN_TPB * SCAN_EPT + t * SCAN_EPT;
    int v[SCAN_EPT];
    int tot = 0;
    #pragma unroll
    for (int j = 0; j < SCAN_EPT; ++j) {
        int idx = base + j;
        v[j] = (idx < N) ? hist[idx] : 0;
        tot += v[j];
    }
    sdata[t] = tot;
    __syncthreads();
    for (int off = 1; off < SCAN_TPB; off <<= 1) {
        int xv = (t >= off) ? sdata[t - off] : 0;
        __syncthreads();
        sdata[t] += xv;
        __syncthreads();
    }
    int run = sdata[t] - tot;
    #pragma unroll
    for (int j = 0; j < SCAN_EPT; ++j) {
        int idx = base + j;
        if (idx < N) offs[idx] = run;
        run += v[j];
    }
    if (t == SCAN_TPB - 1) blockSums[b] = sdata[t];
}

__global__ __launch_bounds__(256) void scan_blocksums(int* __restrict__ blockSums, int nb)
{
    __shared__ int sdata[256];
    int t = threadIdx.x;
    int orig = (t < nb) ? blockSums[t] : 0;
    sdata[t] = orig;
    __syncthreads();
    for (int off = 1; off < 256; off <<= 1) {
        int xv = (t >= off) ? sdata[t - off] : 0;
        __syncthreads();
        sdata[t] += xv;
        __syncthreads();
    }
    if (t < nb) blockSums[t] = sdata[t] - orig;
}

__global__ __launch_bounds__(256) void scan_add(
    int* __restrict__ offs, const int* __restrict__ blockSums, int N)
{
    int idx = blockIdx.x * blockDim.x + threadIdx.x;
    if (idx < N) offs[idx] += blockSums[idx >> 10];
}

__global__ __launch_bounds__(256) void scatter_kernel(
    const int* __restrict__ ei, int* __restrict__ offs,
    int* __restrict__ ssrc, int E)
{
    int e = blockIdx.x * blockDim.x + threadIdx.x;
    if (e < E) {
        int d = ei[E + e];
        int pos = atomicAdd(&offs[d], 1);
        ssrc[pos] = ei[e];
    }
}

// ---------------- per-node attention aggregation (no atomics) ----------------
__global__ __launch_bounds__(256) void node_agg(
    const int* __restrict__ ssrc,
    const int* __restrict__ endoffs,
    const int* __restrict__ deg,
    const float* __restrict__ Q, const float* __restrict__ K,
    const float* __restrict__ V,
    float* __restrict__ agg, int N)
{
    int node = blockIdx.x * 4 + (threadIdx.x >> 6);
    int lane = threadIdx.x & 63;
    if (node >= N) return;
    int end = endoffs[node];
    int start = end - deg[node];
    float q0 = Q[(size_t)node * 128 + lane];
    float q1 = Q[(size_t)node * 128 + lane + 64];
    float a0 = 0.f, a1 = 0.f;
    int i = start;
    for (; i + 4 <= end; i += 4) {
        int s[4];
        #pragma unroll
        for (int j = 0; j < 4; ++j) s[j] = ssrc[i + j];
        float k0[4], k1[4], v0[4], v1[4];
        #pragma unroll
        for (int j = 0; j < 4; ++j) {
            const float* __restrict__ kp = K + (size_t)s[j] * 128;
            const float* __restrict__ vp = V + (size_t)s[j] * 128;
            k0[j] = kp[lane]; k1[j] = kp[lane + 64];
            v0[j] = vp[lane]; v1[j] = vp[lane + 64];
        }
        float p[4];
        #pragma unroll
        for (int j = 0; j < 4; ++j) p[j] = q0 * k0[j] + q1 * k1[j];
        #pragma unroll
        for (int off = 32; off > 0; off >>= 1) {
            #pragma unroll
            for (int j = 0; j < 4; ++j) p[j] += __shfl_xor(p[j], off);
        }
        #pragma unroll
        for (int j = 0; j < 4; ++j) {
            float c = 1.f / (1.f + __expf(-p[j] * 0.0883883476483184f));
            a0 += c * v0[j]; a1 += c * v1[j];
        }
    }
    for (; i < end; ++i) {
        int s = ssrc[i];
        const float* __restrict__ kp = K + (size_t)s * 128;
        const float* __restrict__ vp = V + (size_t)s * 128;
        float k0 = kp[lane], k1 = kp[lane + 64];
        float v0 = vp[lane], v1 = vp[lane + 64];
        float p = q0 * k0 + q1 * k1;
        #pragma unroll
        for (int off = 32; off > 0; off >>= 1) p += __shfl_xor(p, off);
        float c = 1.f / (1.f + __expf(-p * 0.0883883476483184f));
        a0 += c * v0; a1 += c * v1;
    }
    agg[(size_t)node * 128 + lane] = a0;
    agg[(size_t)node * 128 + lane + 64] = a1;
}

// ------- output GEMM (split-bf16 MFMA) + bias + residual + LayerNorm -------
__global__ __launch_bounds__(256) void out_ln_mfma(
    const float* __restrict__ agg,
    const short* __restrict__ whi, const short* __restrict__ wlo,  // Wo = mat 3
    const float* __restrict__ bo, const float* __restrict__ x,
    const float* __restrict__ gamma, const float* __restrict__ beta,
    float* __restrict__ out, int N)
{
    __shared__ __align__(16) char smem[64 * 136 * 2 * 2];   // 69632 B
    short (*xs_hi)[136] = (short(*)[136])smem;
    short (*xs_lo)[136] = (short(*)[136])(smem + 64 * 136 * 2);
    float (*hs)[132]    = (float(*)[132])smem;               // reused post-GEMM

    const int tid = threadIdx.x;
    const int row0 = blockIdx.x * BM;

    #pragma unroll
    for (int i = 0; i < 8; ++i) {
        int idx = tid + 256 * i;
        int r = idx >> 5;
        int c4 = idx & 31;
        int gr = row0 + r;
        float4 val = make_float4(0.f, 0.f, 0.f, 0.f);
        if (gr < N) val = ((const float4*)(agg + (size_t)gr * 128))[c4];
        short4 h, l;
        h.x = f2bf(val.x); l.x = f2bf(val.x - bf2f(h.x));
        h.y = f2bf(val.y); l.y = f2bf(val.y - bf2f(h.y));
        h.z = f2bf(val.z); l.z = f2bf(val.z - bf2f(h.z));
        h.w = f2bf(val.w); l.w = f2bf(val.w - bf2f(h.w));
        *((short4*)&xs_hi[r][c4 * 4]) = h;
        *((short4*)&xs_lo[r][c4 * 4]) = l;
    }
    __syncthreads();

    const int wid  = tid >> 6;
    const int lane = tid & 63;
    const int n16  = lane & 15;
    const int quad = lane >> 4;
    const short* __restrict__ WH = whi + 3 * 16384;
    const short* __restrict__ WL = wlo + 3 * 16384;

    const f32x4 zero = {0.f, 0.f, 0.f, 0.f};
    f32x4 acc[4][2];
    #pragma unroll
    for (int t = 0; t < 4; ++t) { acc[t][0] = zero; acc[t][1] = zero; }

    #pragma unroll
    for (int kc = 0; kc < 4; ++kc) {
        int k0 = kc * 32 + quad * 8;
        bfrag ah[4], al[4], bh[2], bl[2];
        #pragma unroll
        for (int t = 0; t < 4; ++t) {
            ah[t] = *((const bfrag*)&xs_hi[t * 16 + n16][k0]);
            al[t] = *((const bfrag*)&xs_lo[t * 16 + n16][k0]);
        }
        #pragma unroll
        for (int c = 0; c < 2; ++c) {
            int wr = (wid * 2 + c) * 16 + n16;
            bh[c] = *((const bfrag*)(WH + wr * 128 + k0));
            bl[c] = *((const bfrag*)(WL + wr * 128 + k0));
        }
        #pragma unroll
        for (int t = 0; t < 4; ++t)
            #pragma unroll
            for (int c = 0; c < 2; ++c) {
                acc[t][c] = __builtin_amdgcn_mfma_f32_16x16x32_bf16(ah[t], bh[c], acc[t][c], 0, 0, 0);
                acc[t][c] = __builtin_amdgcn_mfma_f32_16x16x32_bf16(al[t], bh[c], acc[t][c], 0, 0, 0);
                acc[t][c] = __builtin_amdgcn_mfma_f32_16x16x32_bf16(ah[t], bl[c], acc[t][c], 0, 0, 0);
            }
    }
    __syncthreads();   // all xs reads done before hs overwrite

    #pragma unroll
    for (int t = 0; t < 4; ++t)
        #pragma unroll
        for (int r = 0; r < 4; ++r) {
            hs[t * 16 + quad * 4 + r][(wid * 2 + 0) * 16 + n16] = acc[t][0][r];
            hs[t * 16 + quad * 4 + r][(wid * 2 + 1) * 16 + n16] = acc[t][1][r];
        }
    __syncthreads();

    // LayerNorm: 4 threads per row, each covers 32 cols; h = gemm + bo + x
    {
        int r = tid >> 2;
        int qd = tid & 3;
        int gr = row0 + r;
        float sum = 0.f, sq = 0.f;
        #pragma unroll
        for (int c = 0; c < 32; c += 4) {
            float4 g4 = *((float4*)&hs[r][qd * 32 + c]);
            float4 b4 = *((const float4*)(bo + qd * 32 + c));
            float4 x4 = make_float4(0.f, 0.f, 0.f, 0.f);
            if (gr < N) x4 = *((const float4*)(x + (size_t)gr * 128 + qd * 32 + c));
            float4 h = make_float4(g4.x + b4.x + x4.x, g4.y + b4.y + x4.y,
                                   g4.z + b4.z + x4.z, g4.w + b4.w + x4.w);
            *((float4*)&hs[r][qd * 32 + c]) = h;
            sum += h.x + h.y + h.z + h.w;
            sq += h.x * h.x + h.y * h.y + h.z * h.z + h.w * h.w;
        }
        sum += __shfl_xor(sum, 1); sum += __shfl_xor(sum, 2);
        sq  += __shfl_xor(sq, 1);  sq  += __shfl_xor(sq, 2);
        float mu = sum * (1.f / 128.f);
        float var = sq * (1.f / 128.f) - mu * mu;
        float rs = rsqrtf(var + 1e-5f);
        if (gr < N) {
            #pragma unroll
            for (int c = 0; c < 32; c += 4) {
                float4 h = *((float4*)&hs[r][qd * 32 + c]);
                float4 g = *((const float4*)(gamma + qd * 32 + c));
                float4 b = *((const float4*)(beta + qd * 32 + c));
                float4 o = make_float4((h.x - mu) * rs * g.x + b.x,
                                       (h.y - mu) * rs * g.y + b.y,
                                       (h.z - mu) * rs * g.z + b.z,
                                       (h.w - mu) * rs * g.w + b.w);
                *((float4*)(out + (size_t)gr * 128 + qd * 32 + c)) = o;
            }
        }
    }
}

extern "C" void kernel_launch(void* const* d_in, const int* in_sizes, int n_in,
                              void* d_out, int out_size, void* d_ws, size_t ws_size,
                              hipStream_t stream) {
    const float* x     = (const float*)d_in[0];
    const int*   ei    = (const int*)d_in[1];
    const float* Wq    = (const float*)d_in[2];
    const float* Wk    = (const float*)d_in[3];
    const float* Wv    = (const float*)d_in[4];
    const float* Wo    = (const float*)d_in[5];
    const float* bo    = (const float*)d_in[6];
    const float* gamma = (const float*)d_in[7];
    const float* beta  = (const float*)d_in[8];
    const int N = in_sizes[0] / 128;
    const int E = in_sizes[1] / 2;
    const size_t ND = (size_t)N * 128;

    // workspace: Q,K,V,agg (102.4 MB) + ints (~2.8 MB) + whi/wlo (256 KB)
    float* ws  = (float*)d_ws;
    float* Q   = ws;
    float* Kb  = Q  + ND;
    float* V   = Kb + ND;
    float* agg = V  + ND;
    int* hist      = (int*)(agg + ND);
    int* offs      = hist + N;
    int* blockSums = offs + N;        // 256 ints
    int* ssrc      = blockSums + 256; // E ints
    short* whi     = (short*)(ssrc + E);       // 4*16384 shorts
    short* wlo     = whi + 4 * 16384;

    hipMemsetAsync(hist, 0, (size_t)N * sizeof(int), stream);

    prep_weights<<<256, 256, 0, stream>>>(Wq, Wk, Wv, Wo, whi, wlo);

    const int gq = (N + BM - 1) / BM;
    qkv_mfma<<<gq, 256, 0, stream>>>(x, whi, wlo, Q, Kb, V, N);

    // counting sort by dst
    hist_kernel<<<(E + 255) / 256, 256, 0, stream>>>(ei, hist, E);
    const int nScanBlocks = (N + SCAN_TPB * SCAN_EPT - 1) / (SCAN_TPB * SCAN_EPT);
    scan_partial<<<nScanBlocks, SCAN_TPB, 0, stream>>>(hist, offs, blockSums, N);
    scan_blocksums<<<1, 256, 0, stream>>>(blockSums, nScanBlocks);
    scan_add<<<(N + 255) / 256, 256, 0, stream>>>(offs, blockSums, N);
    scatter_kernel<<<(E + 255) / 256, 256, 0, stream>>>(ei, offs, ssrc, E);

    node_agg<<<(N + 3) / 4, 256, 0, stream>>>(ssrc, offs, hist, Q, Kb, V, agg, N);

    out_ln_mfma<<<gq, 256, 0, stream>>>(agg, whi, wlo, bo, x, gamma, beta,
                                        (float*)d_out, N);
}

// Round 5
// 305.694 us; speedup vs baseline: 1.5922x; 1.0445x over previous
//
#include <hip/hip_runtime.h>
#include <math.h>

// N nodes (50000), E edges (600000), D=128.
// Q = x@Wq.T; K = x@Wk.T; V = x@Wv.T  (node-level)
// per edge e=(s->d): c = sigmoid(dot(Q[d],K[s])/sqrt(128)); agg[d] += c*V[s]
// out = LN(x + agg@Wo.T + bo) * gamma + beta
//
// R2: per-edge f32 atomics hit TCC atomic ceiling -> counting-sort + per-node agg.
// R3: fp32 VALU GEMMs -> split-bf16 MFMA GEMMs (C = xh*wh + xl*wh + xh*wl).
// R4: node_agg gather cache-capacity-bound (K+V fp32 = 51 MB > 32 MB L2 agg,
//     FETCH 294 MB) -> K/V stored bf16: halves bytes, working set 25.6 MB,
//     1 dword load per row per lane (lane covers elements {2l, 2l+1}).

#define BM 64

typedef __attribute__((ext_vector_type(8))) short bfrag;   // 8 bf16 = 4 VGPRs
typedef __attribute__((ext_vector_type(4))) float f32x4;

__device__ __forceinline__ short f2bf(float f) {
    union { float f; unsigned u; } v; v.f = f;
    unsigned r = v.u + 0x7FFFu + ((v.u >> 16) & 1u);   // round-to-nearest-even
    return (short)(r >> 16);
}
__device__ __forceinline__ float bf2f(short h) {
    union { unsigned u; float f; } v;
    v.u = ((unsigned)(unsigned short)h) << 16;
    return v.f;
}
// unpack packed pair of bf16 (low addr = low bits) to two floats
__device__ __forceinline__ float2 bfpair(unsigned w) {
    union { unsigned u; float f; } lo, hi;
    lo.u = w << 16;
    hi.u = w & 0xffff0000u;
    return make_float2(lo.f, hi.f);
}

// ---------------- weight prep: fp32 -> bf16 hi/lo, 4 matrices ----------------
__global__ __launch_bounds__(256) void prep_weights(
    const float* __restrict__ Wq, const float* __restrict__ Wk,
    const float* __restrict__ Wv, const float* __restrict__ Wo,
    short* __restrict__ whi, short* __restrict__ wlo)
{
    int g = blockIdx.x * 256 + threadIdx.x;   // grid = 256 blocks -> 65536
    const float* Ws[4] = {Wq, Wk, Wv, Wo};
    float f = Ws[g >> 14][g & 16383];
    short h = f2bf(f);
    short l = f2bf(f - bf2f(h));
    whi[g] = h; wlo[g] = l;
}

// ---------------- fused QKV projection via split-bf16 MFMA ----------------
// Q written fp32; K,V written bf16 (consumed by node_agg as packed pairs).
__global__ __launch_bounds__(256) void qkv_mfma(
    const float* __restrict__ x,
    const short* __restrict__ whi, const short* __restrict__ wlo,
    float* __restrict__ Q, unsigned short* __restrict__ K16,
    unsigned short* __restrict__ V16, int N)
{
    __shared__ short xs_hi[64][136];   // +8 pad: row 272 B -> 2-way LDS (free)
    __shared__ short xs_lo[64][136];

    const int tid = threadIdx.x;
    const int row0 = blockIdx.x * BM;

    #pragma unroll
    for (int i = 0; i < 8; ++i) {
        int idx = tid + 256 * i;
        int r = idx >> 5;
        int c4 = idx & 31;
        int gr = row0 + r;
        float4 val = make_float4(0.f, 0.f, 0.f, 0.f);
        if (gr < N) val = ((const float4*)(x + (size_t)gr * 128))[c4];
        short4 h, l;
        h.x = f2bf(val.x); l.x = f2bf(val.x - bf2f(h.x));
        h.y = f2bf(val.y); l.y = f2bf(val.y - bf2f(h.y));
        h.z = f2bf(val.z); l.z = f2bf(val.z - bf2f(h.z));
        h.w = f2bf(val.w); l.w = f2bf(val.w - bf2f(h.w));
        *((short4*)&xs_hi[r][c4 * 4]) = h;
        *((short4*)&xs_lo[r][c4 * 4]) = l;
    }
    __syncthreads();

    const int wid  = tid >> 6;
    const int lane = tid & 63;
    const int n16  = lane & 15;
    const int quad = lane >> 4;

    #pragma unroll 1
    for (int mat = 0; mat < 3; ++mat) {
        const short* __restrict__ WH = whi + mat * 16384;
        const short* __restrict__ WL = wlo + mat * 16384;
        const f32x4 zero = {0.f, 0.f, 0.f, 0.f};
        f32x4 acc[4][2];
        #pragma unroll
        for (int t = 0; t < 4; ++t) { acc[t][0] = zero; acc[t][1] = zero; }

        #pragma unroll
        for (int kc = 0; kc < 4; ++kc) {
            int k0 = kc * 32 + quad * 8;
            bfrag ah[4], al[4], bh[2], bl[2];
            #pragma unroll
            for (int t = 0; t < 4; ++t) {
                ah[t] = *((const bfrag*)&xs_hi[t * 16 + n16][k0]);
                al[t] = *((const bfrag*)&xs_lo[t * 16 + n16][k0]);
            }
            #pragma unroll
            for (int c = 0; c < 2; ++c) {
                int wr = (wid * 2 + c) * 16 + n16;
                bh[c] = *((const bfrag*)(WH + wr * 128 + k0));
                bl[c] = *((const bfrag*)(WL + wr * 128 + k0));
            }
            #pragma unroll
            for (int t = 0; t < 4; ++t)
                #pragma unroll
                for (int c = 0; c < 2; ++c) {
                    acc[t][c] = __builtin_amdgcn_mfma_f32_16x16x32_bf16(ah[t], bh[c], acc[t][c], 0, 0, 0);
                    acc[t][c] = __builtin_amdgcn_mfma_f32_16x16x32_bf16(al[t], bh[c], acc[t][c], 0, 0, 0);
                    acc[t][c] = __builtin_amdgcn_mfma_f32_16x16x32_bf16(ah[t], bl[c], acc[t][c], 0, 0, 0);
                }
        }
        #pragma unroll
        for (int t = 0; t < 4; ++t)
            #pragma unroll
            for (int r = 0; r < 4; ++r) {
                int grow = row0 + t * 16 + quad * 4 + r;
                if (grow < N) {
                    int c0 = (wid * 2 + 0) * 16 + n16;
                    int c1 = (wid * 2 + 1) * 16 + n16;
                    if (mat == 0) {
                        Q[(size_t)grow * 128 + c0] = acc[t][0][r];
                        Q[(size_t)grow * 128 + c1] = acc[t][1][r];
                    } else {
                        unsigned short* Cb = (mat == 1) ? K16 : V16;
                        Cb[(size_t)grow * 128 + c0] = (unsigned short)f2bf(acc[t][0][r]);
                        Cb[(size_t)grow * 128 + c1] = (unsigned short)f2bf(acc[t][1][r]);
                    }
                }
            }
    }
}

// ---------------- counting sort of edges by dst ----------------
__global__ __launch_bounds__(256) void hist_kernel(
    const int* __restrict__ ei, int* __restrict__ hist, int E)
{
    int e = blockIdx.x * blockDim.x + threadIdx.x;
    if (e < E) atomicAdd(&hist[ei[E + e]], 1);
}

#define SCAN_TPB 256
#define SCAN_EPT 4   // 1024 elements per scan block

__global__ __launch_bounds__(SCAN_TPB) void scan_partial(
    const int* __restrict__ hist, int* __restrict__ offs,
    int* __restrict__ blockSums, int N)
{
    __shared__ int sdata[SCAN_TPB];
    int b = blockIdx.x;
    int t = threadIdx.x;
    int base = b * SCAN_TPB * SCAN_EPT + t * SCAN_EPT;
    int v[SCAN_EPT];
    int tot = 0;
    #pragma unroll
    for (int j = 0; j < SCAN_EPT; ++j) {
        int idx = base + j;
        v[j] = (idx < N) ? hist[idx] : 0;
        tot += v[j];
    }
    sdata[t] = tot;
    __syncthreads();
    for (int off = 1; off < SCAN_TPB; off <<= 1) {
        int xv = (t >= off) ? sdata[t - off] : 0;
        __syncthreads();
        sdata[t] += xv;
        __syncthreads();
    }
    int run = sdata[t] - tot;
    #pragma unroll
    for (int j = 0; j < SCAN_EPT; ++j) {
        int idx = base + j;
        if (idx < N) offs[idx] = run;
        run += v[j];
    }
    if (t == SCAN_TPB - 1) blockSums[b] = sdata[t];
}

__global__ __launch_bounds__(256) void scan_blocksums(int* __restrict__ blockSums, int nb)
{
    __shared__ int sdata[256];
    int t = threadIdx.x;
    int orig = (t < nb) ? blockSums[t] : 0;
    sdata[t] = orig;
    __syncthreads();
    for (int off = 1; off < 256; off <<= 1) {
        int xv = (t >= off) ? sdata[t - off] : 0;
        __syncthreads();
        sdata[t] += xv;
        __syncthreads();
    }
    if (t < nb) blockSums[t] = sdata[t] - orig;
}

__global__ __launch_bounds__(256) void scan_add(
    int* __restrict__ offs, const int* __restrict__ blockSums, int N)
{
    int idx = blockIdx.x * blockDim.x + threadIdx.x;
    if (idx < N) offs[idx] += blockSums[idx >> 10];
}

__global__ __launch_bounds__(256) void scatter_kernel(
    const int* __restrict__ ei, int* __restrict__ offs,
    int* __restrict__ ssrc, int E)
{
    int e = blockIdx.x * blockDim.x + threadIdx.x;
    if (e < E) {
        int d = ei[E + e];
        int pos = atomicAdd(&offs[d], 1);
        ssrc[pos] = ei[e];
    }
}

// ---------------- per-node attention aggregation (no atomics) ----------------
// one wave per dst node; lane covers elements {2*lane, 2*lane+1}; K/V bf16:
// one dword load per row per lane. 8-edge batches for memory-level parallelism.
#define NB 8
__global__ __launch_bounds__(256) void node_agg(
    const int* __restrict__ ssrc,
    const int* __restrict__ endoffs,
    const int* __restrict__ deg,
    const float* __restrict__ Q, const unsigned short* __restrict__ K16,
    const unsigned short* __restrict__ V16,
    float* __restrict__ agg, int N)
{
    int node = blockIdx.x * 4 + (threadIdx.x >> 6);
    int lane = threadIdx.x & 63;
    if (node >= N) return;
    int end = endoffs[node];
    int start = end - deg[node];
    float2 q = *((const float2*)(Q + (size_t)node * 128 + lane * 2));
    float a0 = 0.f, a1 = 0.f;
    int i = start;
    for (; i + NB <= end; i += NB) {
        int s[NB];
        #pragma unroll
        for (int j = 0; j < NB; ++j) s[j] = ssrc[i + j];
        unsigned kw[NB], vw[NB];
        #pragma unroll
        for (int j = 0; j < NB; ++j) {
            kw[j] = *((const unsigned*)(K16 + (size_t)s[j] * 128 + lane * 2));
            vw[j] = *((const unsigned*)(V16 + (size_t)s[j] * 128 + lane * 2));
        }
        float p[NB];
        #pragma unroll
        for (int j = 0; j < NB; ++j) {
            float2 k = bfpair(kw[j]);
            p[j] = q.x * k.x + q.y * k.y;
        }
        #pragma unroll
        for (int off = 32; off > 0; off >>= 1) {
            #pragma unroll
            for (int j = 0; j < NB; ++j) p[j] += __shfl_xor(p[j], off);
        }
        #pragma unroll
        for (int j = 0; j < NB; ++j) {
            float c = 1.f / (1.f + __expf(-p[j] * 0.0883883476483184f));
            float2 v = bfpair(vw[j]);
            a0 += c * v.x; a1 += c * v.y;
        }
    }
    for (; i < end; ++i) {
        int s = ssrc[i];
        float2 k = bfpair(*((const unsigned*)(K16 + (size_t)s * 128 + lane * 2)));
        float2 v = bfpair(*((const unsigned*)(V16 + (size_t)s * 128 + lane * 2)));
        float p = q.x * k.x + q.y * k.y;
        #pragma unroll
        for (int off = 32; off > 0; off >>= 1) p += __shfl_xor(p, off);
        float c = 1.f / (1.f + __expf(-p * 0.0883883476483184f));
        a0 += c * v.x; a1 += c * v.y;
    }
    *((float2*)(agg + (size_t)node * 128 + lane * 2)) = make_float2(a0, a1);
}

// ------- output GEMM (split-bf16 MFMA) + bias + residual + LayerNorm -------
__global__ __launch_bounds__(256) void out_ln_mfma(
    const float* __restrict__ agg,
    const short* __restrict__ whi, const short* __restrict__ wlo,  // Wo = mat 3
    const float* __restrict__ bo, const float* __restrict__ x,
    const float* __restrict__ gamma, const float* __restrict__ beta,
    float* __restrict__ out, int N)
{
    __shared__ __align__(16) char smem[64 * 136 * 2 * 2];   // 69632 B
    short (*xs_hi)[136] = (short(*)[136])smem;
    short (*xs_lo)[136] = (short(*)[136])(smem + 64 * 136 * 2);
    float (*hs)[132]    = (float(*)[132])smem;               // reused post-GEMM

    const int tid = threadIdx.x;
    const int row0 = blockIdx.x * BM;

    #pragma unroll
    for (int i = 0; i < 8; ++i) {
        int idx = tid + 256 * i;
        int r = idx >> 5;
        int c4 = idx & 31;
        int gr = row0 + r;
        float4 val = make_float4(0.f, 0.f, 0.f, 0.f);
        if (gr < N) val = ((const float4*)(agg + (size_t)gr * 128))[c4];
        short4 h, l;
        h.x = f2bf(val.x); l.x = f2bf(val.x - bf2f(h.x));
        h.y = f2bf(val.y); l.y = f2bf(val.y - bf2f(h.y));
        h.z = f2bf(val.z); l.z = f2bf(val.z - bf2f(h.z));
        h.w = f2bf(val.w); l.w = f2bf(val.w - bf2f(h.w));
        *((short4*)&xs_hi[r][c4 * 4]) = h;
        *((short4*)&xs_lo[r][c4 * 4]) = l;
    }
    __syncthreads();

    const int wid  = tid >> 6;
    const int lane = tid & 63;
    const int n16  = lane & 15;
    const int quad = lane >> 4;
    const short* __restrict__ WH = whi + 3 * 16384;
    const short* __restrict__ WL = wlo + 3 * 16384;

    const f32x4 zero = {0.f, 0.f, 0.f, 0.f};
    f32x4 acc[4][2];
    #pragma unroll
    for (int t = 0; t < 4; ++t) { acc[t][0] = zero; acc[t][1] = zero; }

    #pragma unroll
    for (int kc = 0; kc < 4; ++kc) {
        int k0 = kc * 32 + quad * 8;
        bfrag ah[4], al[4], bh[2], bl[2];
        #pragma unroll
        for (int t = 0; t < 4; ++t) {
            ah[t] = *((const bfrag*)&xs_hi[t * 16 + n16][k0]);
            al[t] = *((const bfrag*)&xs_lo[t * 16 + n16][k0]);
        }
        #pragma unroll
        for (int c = 0; c < 2; ++c) {
            int wr = (wid * 2 + c) * 16 + n16;
            bh[c] = *((const bfrag*)(WH + wr * 128 + k0));
            bl[c] = *((const bfrag*)(WL + wr * 128 + k0));
        }
        #pragma unroll
        for (int t = 0; t < 4; ++t)
            #pragma unroll
            for (int c = 0; c < 2; ++c) {
                acc[t][c] = __builtin_amdgcn_mfma_f32_16x16x32_bf16(ah[t], bh[c], acc[t][c], 0, 0, 0);
                acc[t][c] = __builtin_amdgcn_mfma_f32_16x16x32_bf16(al[t], bh[c], acc[t][c], 0, 0, 0);
                acc[t][c] = __builtin_amdgcn_mfma_f32_16x16x32_bf16(ah[t], bl[c], acc[t][c], 0, 0, 0);
            }
    }
    __syncthreads();   // all xs reads done before hs overwrite

    #pragma unroll
    for (int t = 0; t < 4; ++t)
        #pragma unroll
        for (int r = 0; r < 4; ++r) {
            hs[t * 16 + quad * 4 + r][(wid * 2 + 0) * 16 + n16] = acc[t][0][r];
            hs[t * 16 + quad * 4 + r][(wid * 2 + 1) * 16 + n16] = acc[t][1][r];
        }
    __syncthreads();

    {
        int r = tid >> 2;
        int qd = tid & 3;
        int gr = row0 + r;
        float sum = 0.f, sq = 0.f;
        #pragma unroll
        for (int c = 0; c < 32; c += 4) {
            float4 g4 = *((float4*)&hs[r][qd * 32 + c]);
            float4 b4 = *((const float4*)(bo + qd * 32 + c));
            float4 x4 = make_float4(0.f, 0.f, 0.f, 0.f);
            if (gr < N) x4 = *((const float4*)(x + (size_t)gr * 128 + qd * 32 + c));
            float4 h = make_float4(g4.x + b4.x + x4.x, g4.y + b4.y + x4.y,
                                   g4.z + b4.z + x4.z, g4.w + b4.w + x4.w);
            *((float4*)&hs[r][qd * 32 + c]) = h;
            sum += h.x + h.y + h.z + h.w;
            sq += h.x * h.x + h.y * h.y + h.z * h.z + h.w * h.w;
        }
        sum += __shfl_xor(sum, 1); sum += __shfl_xor(sum, 2);
        sq  += __shfl_xor(sq, 1);  sq  += __shfl_xor(sq, 2);
        float mu = sum * (1.f / 128.f);
        float var = sq * (1.f / 128.f) - mu * mu;
        float rs = rsqrtf(var + 1e-5f);
        if (gr < N) {
            #pragma unroll
            for (int c = 0; c < 32; c += 4) {
                float4 h = *((float4*)&hs[r][qd * 32 + c]);
                float4 g = *((const float4*)(gamma + qd * 32 + c));
                float4 b = *((const float4*)(beta + qd * 32 + c));
                float4 o = make_float4((h.x - mu) * rs * g.x + b.x,
                                       (h.y - mu) * rs * g.y + b.y,
                                       (h.z - mu) * rs * g.z + b.z,
                                       (h.w - mu) * rs * g.w + b.w);
                *((float4*)(out + (size_t)gr * 128 + qd * 32 + c)) = o;
            }
        }
    }
}

extern "C" void kernel_launch(void* const* d_in, const int* in_sizes, int n_in,
                              void* d_out, int out_size, void* d_ws, size_t ws_size,
                              hipStream_t stream) {
    const float* x     = (const float*)d_in[0];
    const int*   ei    = (const int*)d_in[1];
    const float* Wq    = (const float*)d_in[2];
    const float* Wk    = (const float*)d_in[3];
    const float* Wv    = (const float*)d_in[4];
    const float* Wo    = (const float*)d_in[5];
    const float* bo    = (const float*)d_in[6];
    const float* gamma = (const float*)d_in[7];
    const float* beta  = (const float*)d_in[8];
    const int N = in_sizes[0] / 128;
    const int E = in_sizes[1] / 2;
    const size_t ND = (size_t)N * 128;

    // workspace: Q fp32 (25.6MB) + K16/V16 bf16 (12.8MB each) + agg (25.6MB)
    //            + ints (~2.8 MB) + whi/wlo (256 KB)
    float* ws  = (float*)d_ws;
    float* Q   = ws;
    unsigned short* K16 = (unsigned short*)(Q + ND);     // ND ushorts
    unsigned short* V16 = K16 + ND;                      // ND ushorts
    float* agg = (float*)(V16 + ND);
    int* hist      = (int*)(agg + ND);
    int* offs      = hist + N;
    int* blockSums = offs + N;        // 256 ints
    int* ssrc      = blockSums + 256; // E ints
    short* whi     = (short*)(ssrc + E);       // 4*16384 shorts
    short* wlo     = whi + 4 * 16384;

    hipMemsetAsync(hist, 0, (size_t)N * sizeof(int), stream);

    prep_weights<<<256, 256, 0, stream>>>(Wq, Wk, Wv, Wo, whi, wlo);

    const int gq = (N + BM - 1) / BM;
    qkv_mfma<<<gq, 256, 0, stream>>>(x, whi, wlo, Q, K16, V16, N);

    // counting sort by dst
    hist_kernel<<<(E + 255) / 256, 256, 0, stream>>>(ei, hist, E);
    const int nScanBlocks = (N + SCAN_TPB * SCAN_EPT - 1) / (SCAN_TPB * SCAN_EPT);
    scan_partial<<<nScanBlocks, SCAN_TPB, 0, stream>>>(hist, offs, blockSums, N);
    scan_blocksums<<<1, 256, 0, stream>>>(blockSums, nScanBlocks);
    scan_add<<<(N + 255) / 256, 256, 0, stream>>>(offs, blockSums, N);
    scatter_kernel<<<(E + 255) / 256, 256, 0, stream>>>(ei, offs, ssrc, E);

    node_agg<<<(N + 3) / 4, 256, 0, stream>>>(ssrc, offs, hist, Q, K16, V16, agg, N);

    out_ln_mfma<<<gq, 256, 0, stream>>>(agg, whi, wlo, bo, x, gamma, beta,
                                        (float*)d_out, N);
}